// Round 7
// baseline (288.743 us; speedup 1.0000x reference)
//
#include <hip/hip_runtime.h>
#include <hip/hip_bf16.h>

// Problem constants (N=2, C=256, H=W=64) — float32 I/O per reference.
#define NBATCH 2
#define CCH    256
#define LLEN   4096      // H*W
#define NGROUP 8
#define CPG    32        // C / NGROUP
#define NHEAD  4
#define HD     64        // C / NHEAD
#define GEPS   1e-5f
// q pre-scale: hd^-0.5 * log2(e); scores feed v_exp_f32 (2^x) directly.
#define QSCALE 0.18033688011112042f

// Generic MFMA fragment tiling (for 16x16x32 bf16): a [R x 256ch] tensor is
// stored as tiles [r16][c32] of 512 ushorts; element (r, c) sits at
// tile*512 + ((r&15) + 16*((c>>3)&3))*8 + (c&7).

typedef short bf16x8 __attribute__((ext_vector_type(8)));
typedef float f32x4  __attribute__((ext_vector_type(4)));

__device__ __forceinline__ unsigned short f2b(float f) {
  unsigned u = __float_as_uint(f);
  u += 0x7FFFu + ((u >> 16) & 1u);
  return (unsigned short)(u >> 16);
}
// Native packed f32->bf16 convert (gfx950).
__device__ __forceinline__ unsigned cvtpk(float lo, float hi) {
  unsigned r;
  asm("v_cvt_pk_bf16_f32 %0, %1, %2" : "=v"(r) : "v"(lo), "v"(hi));
  return r;
}
__device__ __forceinline__ float exp2_(float x) {
#if __has_builtin(__builtin_amdgcn_exp2f)
  return __builtin_amdgcn_exp2f(x);
#else
  return exp2f(x);
#endif
}

// ------- Fused GN-stats + GN-apply + weight-tiling + QKV GEMM.
//   Grid = 1024 blocks = EXACTLY 4 blocks/CU x 256 CU with
//   __launch_bounds__(256,4) (128-VGPR cap; qkv phase ~90) -> all blocks
//   co-resident -> spin barriers deadlock-free. r5's bug was the (256,8)
//   64-VGPR cap (total spill, VGPR_Count=12); phases here re-read x
//   (L2-hot) instead of holding it across the spin.
//   Determinism: per-block partials in unique part[] slots, fixed-order
//   wave reduce (no float atomics).
//   Cross-XCD visibility: writers __threadfence() + agent release-add;
//   readers agent acquire-load (L2 wb/inv handled by the memory model). -------
__global__ __launch_bounds__(256, 4) void gnqkv_kernel(
    const float* __restrict__ x, const float* __restrict__ gw,
    const float* __restrict__ gb,
    const float* __restrict__ qw, const float* __restrict__ kw,
    const float* __restrict__ vw, const float* __restrict__ pw,
    const float* __restrict__ qb, const float* __restrict__ kb,
    const float* __restrict__ vb, const float* __restrict__ pb,
    const int* __restrict__ mask,
    unsigned short* __restrict__ xn16, unsigned short* __restrict__ w16,
    float* __restrict__ bias_ws, float* __restrict__ part,
    unsigned* __restrict__ gcnt,
    unsigned short* __restrict__ q16, unsigned short* __restrict__ k16,
    unsigned short* __restrict__ v16, float* __restrict__ out2) {
  __shared__ float tile[32][68];
  __shared__ float sred[8];
  __shared__ float smv[2];
  const int bx = blockIdx.x, t = threadIdx.x;
  const int lx = bx & 63, cy = (bx >> 6) & 7, n = bx >> 9;
  const int l0 = lx * 64, c0 = cy * 32;
  const int g = n * 8 + cy;
  const int cl = t >> 3, l8 = t & 7;
  const float* xrow = x + ((size_t)n * CCH + c0 + cl) * LLEN + l0;

  // ---- phase 1: this block's 32ch x 64l partial sums -> part[] slot ----
  {
    const float4 va = ((const float4*)xrow)[l8];
    const float4 vc = ((const float4*)xrow)[l8 + 8];
    float s = va.x + va.y + va.z + va.w + vc.x + vc.y + vc.z + vc.w;
    float ss = 0.f;
    ss = fmaf(va.x, va.x, ss); ss = fmaf(va.y, va.y, ss);
    ss = fmaf(va.z, va.z, ss); ss = fmaf(va.w, va.w, ss);
    ss = fmaf(vc.x, vc.x, ss); ss = fmaf(vc.y, vc.y, ss);
    ss = fmaf(vc.z, vc.z, ss); ss = fmaf(vc.w, vc.w, ss);
#pragma unroll
    for (int off = 32; off; off >>= 1) {
      s  += __shfl_down(s, off);
      ss += __shfl_down(ss, off);
    }
    if ((t & 63) == 0) { sred[t >> 6] = s; sred[4 + (t >> 6)] = ss; }
    __syncthreads();
    if (t == 0) {
      part[(g * 64 + lx) * 2 + 0] = sred[0] + sred[1] + sred[2] + sred[3];
      part[(g * 64 + lx) * 2 + 1] = sred[4] + sred[5] + sred[6] + sred[7];
      __threadfence();
      __hip_atomic_fetch_add(&gcnt[g], 1u, __ATOMIC_RELEASE,
                             __HIP_MEMORY_SCOPE_AGENT);
    }
  }
  // ---- distributed side work (hides the spin window) ----
  if (t < 64) {
    const int idx = bx * 64 + t;               // float4 units; 65536 total
    const int m = idx >> 14;
    const int rem = idx & 16383;
    const int cout = rem >> 6;
    const int ch4 = (rem & 63) << 2;
    const float* srcp = (m == 0) ? qw : (m == 1) ? kw : (m == 2) ? vw : pw;
    const float sc = (m == 0) ? QSCALE : 1.0f;
    const float4 v = ((const float4*)srcp)[(size_t)cout * 64 + (ch4 >> 2)];
    unsigned short* dst = w16 +
        ((size_t)(m * 16 + (cout >> 4)) * 8 + (ch4 >> 5)) * 512 +
        ((cout & 15) + 16 * ((ch4 >> 3) & 3)) * 8 + (ch4 & 7);
    uint2 wd;
    wd.x = cvtpk(v.x * sc, v.y * sc);
    wd.y = cvtpk(v.z * sc, v.w * sc);
    *(uint2*)dst = wd;
  } else if (t < 72) {
    const int i = bx * 8 + (t - 64);
    out2[i] = (float)mask[i];
  } else if (t == 72) {
    const int m = bx >> 8, c = bx & 255;
    bias_ws[bx] = (m == 0) ? qb[c] * QSCALE : (m == 1) ? kb[c]
                : (m == 2) ? vb[c] : pb[c];
  }
  // ---- barrier 1: group's 64 partials ready ----
  if (t == 0) {
    while (__hip_atomic_load(&gcnt[g], __ATOMIC_ACQUIRE,
                             __HIP_MEMORY_SCOPE_AGENT) < 64u)
      __builtin_amdgcn_s_sleep(4);
  }
  __syncthreads();
  // wave 0: deterministic fixed-order reduce of the 64 slots
  if (t < 64) {
    float s = part[(g * 64 + t) * 2 + 0];
    float ss = part[(g * 64 + t) * 2 + 1];
#pragma unroll
    for (int off = 32; off; off >>= 1) {
      s  += __shfl_down(s, off);
      ss += __shfl_down(ss, off);
    }
    if (t == 0) {
      const float inv = 1.0f / (float)(CPG * LLEN);
      const float mu = s * inv;
      smv[0] = mu;
      smv[1] = rsqrtf(ss * inv - mu * mu + GEPS);
    }
  }
  __syncthreads();
  // ---- phase 2: re-read x (L2-hot), normalize, LDS transpose, store xn16 ----
  const float aa = smv[1] * gw[c0 + cl];
  const float dd = gb[c0 + cl] - smv[0] * aa;
  {
    float4 u = ((const float4*)xrow)[l8];
    float4 v = ((const float4*)xrow)[l8 + 8];
    u.x = fmaf(u.x, aa, dd); u.y = fmaf(u.y, aa, dd);
    u.z = fmaf(u.z, aa, dd); u.w = fmaf(u.w, aa, dd);
    v.x = fmaf(v.x, aa, dd); v.y = fmaf(v.y, aa, dd);
    v.z = fmaf(v.z, aa, dd); v.w = fmaf(v.w, aa, dd);
    *(float4*)&tile[cl][l8 * 4] = u;
    *(float4*)&tile[cl][(l8 + 8) * 4] = v;
  }
  __syncthreads();
  {
    const int l = t & 63, cg = t >> 6;
    const int labs = l0 + l;
    union { unsigned u[4]; bf16x8 v; } ov;
#pragma unroll
    for (int j = 0; j < 4; j++)
      ov.u[j] = cvtpk(tile[cg * 8 + 2 * j][l], tile[cg * 8 + 2 * j + 1][l]);
    const size_t pos = (((size_t)n * 256 + (labs >> 4)) * 8 + (c0 >> 5)) * 512 +
                       ((labs & 15) + 16 * cg) * 8;
    *(bf16x8*)(xn16 + pos) = ov.v;
  }
  // ---- barrier 2: ALL xn16/w16/bias stores globally visible ----
  __syncthreads();   // drains this block's stores (waitcnt before s_barrier)
  if (t == 0) {
    __threadfence();
    __hip_atomic_fetch_add(&gcnt[16], 1u, __ATOMIC_RELEASE,
                           __HIP_MEMORY_SCOPE_AGENT);
  }
  const int wsel = bx >> 8;                  // 0=q,1=k,2=v, 3=done
  if (wsel >= 3) return;
  if (t == 0) {
    while (__hip_atomic_load(&gcnt[16], __ATOMIC_ACQUIRE,
                             __HIP_MEMORY_SCOPE_AGENT) < 1024u)
      __builtin_amdgcn_s_sleep(4);
  }
  __syncthreads();
  // ---- phase 3: QKV GEMM (r4 body; 32 l-rows per block) ----
  {
    const int lane = t & 63, wv = t >> 6;
    const int col = lane & 15, quad = lane >> 4;
    const int m0 = (bx & 255) * 32;
    const int qn = m0 >> 12;
    const int m16b = (m0 & 4095) >> 4;
    const int ql0 = m0 & 4095;

    const unsigned short* xnb = xn16 + (((size_t)qn * 256 + m16b) * 8) * 512 + lane * 8;
    const unsigned short* wb  = w16 + ((size_t)(wsel * 16 + wv * 4) * 8) * 512 + lane * 8;

    f32x4 acc[2][4];
#pragma unroll
    for (int mt = 0; mt < 2; mt++)
#pragma unroll
      for (int ct = 0; ct < 4; ct++) acc[mt][ct] = {0.f, 0.f, 0.f, 0.f};

#pragma unroll
    for (int kc = 0; kc < 8; kc++) {
      bf16x8 xf[2], wf[4];
      xf[0] = *(const bf16x8*)(xnb + (size_t)kc * 512);
      xf[1] = *(const bf16x8*)(xnb + (size_t)(8 + kc) * 512);
#pragma unroll
      for (int ct = 0; ct < 4; ct++)
        wf[ct] = *(const bf16x8*)(wb + (size_t)(ct * 8 + kc) * 512);
#pragma unroll
      for (int mt = 0; mt < 2; mt++)
#pragma unroll
        for (int ct = 0; ct < 4; ct++)
          acc[mt][ct] = (wsel < 2)
              ? __builtin_amdgcn_mfma_f32_16x16x32_bf16(wf[ct], xf[mt], acc[mt][ct], 0, 0, 0)   // D[cout][l]
              : __builtin_amdgcn_mfma_f32_16x16x32_bf16(xf[mt], wf[ct], acc[mt][ct], 0, 0, 0);  // D[key][vch]
    }

    if (wsel < 2) {
      unsigned short* dst = (wsel == 0) ? q16 : k16;
#pragma unroll
      for (int ct = 0; ct < 4; ct++) {
        const float4 b4 = *(const float4*)&bias_ws[wsel * CCH + wv * 64 + ct * 16 + quad * 4];
#pragma unroll
        for (int mt = 0; mt < 2; mt++) {
          uint2 wd;
          wd.x = cvtpk(acc[mt][ct][0] + b4.x, acc[mt][ct][1] + b4.y);
          wd.y = cvtpk(acc[mt][ct][2] + b4.z, acc[mt][ct][3] + b4.w);
          *(uint2*)(dst + ((size_t)(qn * 256 + m16b + mt) * 8 + wv * 2 + (ct >> 1)) * 512 +
                    (col + 16 * ((ct & 1) * 2 + (quad >> 1))) * 8 + (quad & 1) * 4) = wd;
        }
      }
    } else {
#pragma unroll
      for (int ct = 0; ct < 4; ct++) {
        const float bv = bias_ws[2 * CCH + wv * 64 + ct * 16 + col];
#pragma unroll
        for (int mt = 0; mt < 2; mt++) {
          uint2 wd;
          wd.x = cvtpk(acc[mt][ct][0] + bv, acc[mt][ct][1] + bv);
          wd.y = cvtpk(acc[mt][ct][2] + bv, acc[mt][ct][3] + bv);
          *(uint2*)(v16 + (((size_t)qn * 128 + (ql0 >> 5)) * 16 + wv * 4 + ct) * 512 +
                    (col + 16 * (mt * 2 + (quad >> 1))) * 8 + (quad & 1) * 4) = wd;
        }
      }
    }
  }
}

// ------- Flash attention v9 (unchanged from r6, ~41us). -------
__global__ __launch_bounds__(256, 2) void attn_mfma_kernel(
    const unsigned short* __restrict__ q16,   // Q' tiled, pre-scaled
    const unsigned short* __restrict__ k16,   // K' tiled
    const unsigned short* __restrict__ v16,   // V' tiled
    unsigned short* __restrict__ o16) {       // O' tiled (normalized)
  __shared__ __align__(16) unsigned char shraw[20480];
  f32x4 (*red)[4][64] = (f32x4 (*)[4][64])shraw;                      // 16KB
  f32x4 (*lred)[64] = (f32x4 (*)[64])(shraw + 16384);                 // 4KB
  const int t = threadIdx.x;
  const int lane = t & 63, wv = t >> 6;
  const int col = lane & 15, quad = lane >> 4;
  // Bijective XCD swizzle (512 blocks % 8 == 0): one head per XCD-L2.
  const int fid = blockIdx.y * gridDim.x + blockIdx.x;
  const int nh = fid & 7, qx = fid >> 3;
  const int n = nh >> 2, h = nh & 3;
  const int hc = h * HD;
  const int qt0 = qx * 4;                     // base q16-tile (64 rows)

  const unsigned short* qb = q16 + (size_t)n * (256 * 8 * 512);
  const unsigned short* kb = k16 + (size_t)n * (256 * 8 * 512);
  const unsigned short* vb = v16 + (size_t)n * (128 * 16 * 512);

  bf16x8 bq[4][2];
#pragma unroll
  for (int qt = 0; qt < 4; qt++)
#pragma unroll
    for (int ks = 0; ks < 2; ks++)
      bq[qt][ks] = *(const bf16x8*)(qb + ((size_t)(qt0 + qt) * 8 + h * 2 + ks) * 512 + lane * 8);

  bf16x8 bones;
#pragma unroll
  for (int i = 0; i < 8; i++) bones[i] = (short)0x3F80;   // bf16 1.0
  const f32x4 zf = {0.f, 0.f, 0.f, 0.f};

  f32x4 o[4][4], lacc[4];
#pragma unroll
  for (int qt = 0; qt < 4; qt++) {
    lacc[qt] = {0.f, 0.f, 0.f, 0.f};
#pragma unroll
    for (int ct = 0; ct < 4; ct++) o[qt][ct] = {0.f, 0.f, 0.f, 0.f};
  }

  // Wave-base pointers; chunk c lives at +c*8192 ushorts.
  const unsigned short* kp = kb + ((size_t)(wv * 64) * 8 + h * 2) * 512 + lane * 8;
  const unsigned short* vp = vb + ((size_t)(wv * 32) * 16 + h * 4) * 512 + lane * 8;

  bf16x8 kA[2][2], kB[2][2], vA[4], vB[4];
  unsigned pkA[4][4], pkB[4][4];
  bf16x8 paA[4], paB[4];

  auto loadK = [&](bf16x8 (&kr)[2][2], const unsigned short* p) {
#pragma unroll
    for (int kt = 0; kt < 2; kt++)
#pragma unroll
      for (int ks = 0; ks < 2; ks++)
        kr[kt][ks] = *(const bf16x8*)(p + kt * 4096 + ks * 512);
  };
  auto loadV = [&](bf16x8 (&vv)[4], const unsigned short* p) {
#pragma unroll
    for (int ct = 0; ct < 4; ct++) vv[ct] = *(const bf16x8*)(p + ct * 512);
  };
  // fused QK^T + exp2 + pack: kr -> pk[qt] = {a0,a1,b0,b1}
  auto QKE = [&](unsigned (&pk)[4][4], bf16x8 (&kr)[2][2]) {
#pragma unroll
    for (int qt = 0; qt < 4; qt++) {
      f32x4 sa = __builtin_amdgcn_mfma_f32_16x16x32_bf16(kr[0][0], bq[qt][0], zf, 0, 0, 0);
      sa = __builtin_amdgcn_mfma_f32_16x16x32_bf16(kr[0][1], bq[qt][1], sa, 0, 0, 0);
      f32x4 sb = __builtin_amdgcn_mfma_f32_16x16x32_bf16(kr[1][0], bq[qt][0], zf, 0, 0, 0);
      sb = __builtin_amdgcn_mfma_f32_16x16x32_bf16(kr[1][1], bq[qt][1], sb, 0, 0, 0);
      pk[qt][0] = cvtpk(exp2_(sa[0]), exp2_(sa[1]));
      pk[qt][1] = cvtpk(exp2_(sa[2]), exp2_(sa[3]));
      pk[qt][2] = cvtpk(exp2_(sb[0]), exp2_(sb[1]));
      pk[qt][3] = cvtpk(exp2_(sb[2]), exp2_(sb[3]));
    }
  };
  auto PERM = [&](bf16x8 (&pa)[4], unsigned (&pk)[4][4]) {
#pragma unroll
    for (int qt = 0; qt < 4; qt++) {
      auto r0 = __builtin_amdgcn_permlane32_swap(pk[qt][0], pk[qt][2], false, false);
      auto s0 = __builtin_amdgcn_permlane16_swap(r0[0], r0[1], false, false);
      auto r1 = __builtin_amdgcn_permlane32_swap(pk[qt][1], pk[qt][3], false, false);
      auto s1 = __builtin_amdgcn_permlane16_swap(r1[0], r1[1], false, false);
      union { unsigned u[4]; bf16x8 v; } pu;
      pu.u[0] = s0[0];
      pu.u[1] = s1[0];
      pu.u[2] = s0[1];
      pu.u[3] = s1[1];
      pa[qt] = pu.v;
    }
  };
  auto PV = [&](bf16x8 (&pa)[4], bf16x8 (&vv)[4]) {
    __builtin_amdgcn_s_setprio(1);
#pragma unroll
    for (int qt = 0; qt < 4; qt++) {
      lacc[qt] = __builtin_amdgcn_mfma_f32_16x16x32_bf16(pa[qt], bones, lacc[qt], 0, 0, 0);
#pragma unroll
      for (int ct = 0; ct < 4; ct++)
        o[qt][ct] = __builtin_amdgcn_mfma_f32_16x16x32_bf16(pa[qt], vv[ct], o[qt][ct], 0, 0, 0);
    }
    __builtin_amdgcn_s_setprio(0);
  };

  // prologue: chunk 0 scores, chunk 1 data
  loadK(kA, kp); loadV(vA, vp);
  QKE(pkA, kA);
  loadK(kB, kp + 8192); loadV(vB, vp + 8192);
  // steady: iter finishes chunks it, it+1; computes scores it+1, it+2
  for (int it = 0; it < 30; it += 2) {
    PERM(paA, pkA);
    loadK(kA, kp + 16384);           // K(it+2)
    QKE(pkB, kB);                    // scores(it+1)
    PV(paA, vA);                     // finish chunk it
    loadK(kB, kp + 24576);           // K(it+3)
    loadV(vA, vp + 16384);           // V(it+2)
    PERM(paB, pkB);
    QKE(pkA, kA);                    // scores(it+2)
    PV(paB, vB);                     // finish chunk it+1
    loadV(vB, vp + 24576);           // V(it+3)
    kp += 16384; vp += 16384;
  }
  // epilogue: chunks 30, 31
  PERM(paA, pkA);
  QKE(pkB, kB);
  PV(paA, vA);
  PERM(paB, pkB);
  PV(paB, vB);

  // ---- merge across 4 waves, normalize, store O' tiled ----
  const int cch = hc + wv * 16 + col;
  const int lquad16 = 16 * ((cch >> 3) & 3);
  const size_t ctile = cch >> 5;
#pragma unroll
  for (int qt = 0; qt < 4; qt++) {
    __syncthreads();
#pragma unroll
    for (int ct = 0; ct < 4; ct++) red[wv][ct][lane] = o[qt][ct];
    lred[wv][lane] = lacc[qt];
    __syncthreads();
    f32x4 os = red[0][wv][lane];
    os += red[1][wv][lane];
    os += red[2][wv][lane];
    os += red[3][wv][lane];
    f32x4 ls = lred[0][lane];
    ls += lred[1][lane];
    ls += lred[2][lane];
    ls += lred[3][lane];
    const size_t base = (((size_t)n * 256 + qt0 + qt) * 8 + ctile) * 512 + (cch & 7);
#pragma unroll
    for (int r = 0; r < 4; r++)
      o16[base + ((quad * 4 + r) + lquad16) * 8] = f2b(os[r] / ls[r]);
  }
}

// ------- Proj GEMM, 32-row M-tiles (unchanged). -------
__global__ __launch_bounds__(256, 4) void proj_mfma_kernel(
    const unsigned short* __restrict__ o16,
    const unsigned short* __restrict__ w16,
    const float* __restrict__ pbias,
    const float* __restrict__ x,
    float* __restrict__ out) {
  const int t = threadIdx.x;
  const int lane = t & 63, wv = t >> 6;
  const int col = lane & 15, quad = lane >> 4;
  const int m0 = blockIdx.x * 32;
  const int by = blockIdx.y;
  const int co0 = by * 64;
  const int n = m0 >> 12, l0 = m0 & 4095;

  const unsigned short* ob = o16 + (size_t)n * (256 * 8 * 512);
  const unsigned short* wb = w16 + ((size_t)(48 + by * 4 + wv) * 8) * 512 + lane * 8;

  f32x4 acc[2];
#pragma unroll
  for (int i = 0; i < 2; i++) acc[i] = {0.f, 0.f, 0.f, 0.f};

#pragma unroll
  for (int kc = 0; kc < 8; kc++) {
    const bf16x8 aw = *(const bf16x8*)(wb + (size_t)kc * 512);
#pragma unroll
    for (int lt = 0; lt < 2; lt++) {
      const bf16x8 bo = *(const bf16x8*)(ob + ((size_t)((l0 >> 4) + lt) * 8 + kc) * 512 + lane * 8);
      acc[lt] = __builtin_amdgcn_mfma_f32_16x16x32_bf16(aw, bo, acc[lt], 0, 0, 0);  // D[cout][l]
    }
  }
#pragma unroll
  for (int lt = 0; lt < 2; lt++)
#pragma unroll
    for (int r = 0; r < 4; r++) {
      const int cout = co0 + wv * 16 + quad * 4 + r;
      const size_t idx = ((size_t)(n * CCH + cout)) * LLEN + l0 + lt * 16 + col;
      out[idx] = acc[lt][r] + pbias[cout] + x[idx];
    }
}

extern "C" void kernel_launch(void* const* d_in, const int* in_sizes, int n_in,
                              void* d_out, int out_size, void* d_ws, size_t ws_size,
                              hipStream_t stream) {
  (void)in_sizes; (void)n_in; (void)out_size; (void)ws_size;
  const float* x      = (const float*)d_in[0];
  const int*   mask   = (const int*)d_in[1];
  const float* norm_w = (const float*)d_in[2];
  const float* norm_b = (const float*)d_in[3];
  const float* q_w    = (const float*)d_in[4];
  const float* q_b    = (const float*)d_in[5];
  const float* k_w    = (const float*)d_in[6];
  const float* k_b    = (const float*)d_in[7];
  const float* v_w    = (const float*)d_in[8];
  const float* v_b    = (const float*)d_in[9];
  const float* p_w    = (const float*)d_in[10];
  const float* p_b    = (const float*)d_in[11];

  const size_t TSZ = (size_t)NBATCH * LLEN * CCH;   // 2097152 elements
  unsigned short* xn16 = (unsigned short*)d_ws;     // TSZ (tiled)
  unsigned short* q16  = xn16 + TSZ;                // tiled
  unsigned short* k16  = q16 + TSZ;                 // tiled
  unsigned short* v16  = k16 + TSZ;                 // tiled
  unsigned short* o16  = v16 + TSZ;                 // tiled
  unsigned short* w16  = o16 + TSZ;                 // 4*65536 (tiled)
  float* bias_ws = (float*)(w16 + 4 * 65536);       // 1024 floats
  float* part    = bias_ws + 1024;                  // 2048 floats (16g x 64 x 2)
  unsigned* gcnt = (unsigned*)(part + 2048);        // 17 counters
  // total ~21 MB

  float* out  = (float*)d_out;
  float* out2 = out + TSZ;   // mask chunk

  hipMemsetAsync(gcnt, 0, 17 * sizeof(unsigned), stream);
  gnqkv_kernel<<<1024, 256, 0, stream>>>(
      x, norm_w, norm_b, q_w, k_w, v_w, p_w, q_b, k_b, v_b, p_b,
      mask, xn16, w16, bias_ws, part, gcnt, q16, k16, v16, out2);
  attn_mfma_kernel<<<dim3(LLEN / 64, NBATCH * NHEAD), 256, 0, stream>>>(
      q16, k16, v16, o16);
  proj_mfma_kernel<<<dim3((NBATCH * LLEN) / 32, CCH / 64), 256, 0, stream>>>(
      o16, w16, bias_ws + 768, x, out);
}

// Round 8
// 143.714 us; speedup vs baseline: 2.0091x; 2.0091x over previous
//
#include <hip/hip_runtime.h>
#include <hip/hip_bf16.h>

// Problem constants (N=2, C=256, H=W=64) — float32 I/O per reference.
#define NBATCH 2
#define CCH    256
#define LLEN   4096      // H*W
#define NGROUP 8
#define CPG    32        // C / NGROUP
#define NHEAD  4
#define HD     64        // C / NHEAD
#define GEPS   1e-5f
// q pre-scale: hd^-0.5 * log2(e); scores feed v_exp_f32 (2^x) directly.
#define QSCALE 0.18033688011112042f

// Generic MFMA fragment tiling (for 16x16x32 bf16): a [R x 256ch] tensor is
// stored as tiles [r16][c32] of 512 ushorts; element (r, c) sits at
// tile*512 + ((r&15) + 16*((c>>3)&3))*8 + (c&7).

typedef short bf16x8 __attribute__((ext_vector_type(8)));
typedef float f32x4  __attribute__((ext_vector_type(4)));

__device__ __forceinline__ unsigned short f2b(float f) {
  unsigned u = __float_as_uint(f);
  u += 0x7FFFu + ((u >> 16) & 1u);
  return (unsigned short)(u >> 16);
}
// Native packed f32->bf16 convert (gfx950).
__device__ __forceinline__ unsigned cvtpk(float lo, float hi) {
  unsigned r;
  asm("v_cvt_pk_bf16_f32 %0, %1, %2" : "=v"(r) : "v"(lo), "v"(hi));
  return r;
}
__device__ __forceinline__ float exp2_(float x) {
#if __has_builtin(__builtin_amdgcn_exp2f)
  return __builtin_amdgcn_exp2f(x);
#else
  return exp2f(x);
#endif
}

// ------- setup: GN partial sums only (256 blocks, 16 per group) -------
__global__ __launch_bounds__(256) void setup_kernel(const float* __restrict__ x,
                                                    float* __restrict__ part) {
  __shared__ float rs[4], rss[4];
  const int sb = blockIdx.x;
  const int t = threadIdx.x;
  const int gidx = sb >> 4, sub = sb & 15;
  const float4* xp = (const float4*)(x + (size_t)gidx * (CPG * LLEN)) + (size_t)sub * 2048;
  float s = 0.f, ss = 0.f;
  for (int i = t; i < 2048; i += 256) {
    const float4 v = xp[i];
    s += v.x + v.y + v.z + v.w;
    ss = fmaf(v.x, v.x, ss);
    ss = fmaf(v.y, v.y, ss);
    ss = fmaf(v.z, v.z, ss);
    ss = fmaf(v.w, v.w, ss);
  }
#pragma unroll
  for (int off = 32; off; off >>= 1) {
    s  += __shfl_down(s, off);
    ss += __shfl_down(ss, off);
  }
  if ((t & 63) == 0) { rs[t >> 6] = s; rss[t >> 6] = ss; }
  __syncthreads();
  if (t == 0) {
    part[sb * 2 + 0] = rs[0] + rs[1] + rs[2] + rs[3];
    part[sb * 2 + 1] = rss[0] + rss[1] + rss[2] + rss[3];
  }
}

// ------- GN apply+transpose (blocks 0..1023) | weight tiling+bias
//   (1024..1279) | mask copy (1280..1311). -------
__global__ __launch_bounds__(256) void gn_apply_kernel(
    const float* __restrict__ x, const float* __restrict__ w,
    const float* __restrict__ b, const float* __restrict__ part,
    const float* __restrict__ qw, const float* __restrict__ kw,
    const float* __restrict__ vw, const float* __restrict__ pw,
    const float* __restrict__ qb, const float* __restrict__ kb,
    const float* __restrict__ vb, const float* __restrict__ pb,
    const int* __restrict__ mask,
    unsigned short* __restrict__ xn16, unsigned short* __restrict__ w16,
    float* __restrict__ bias_ws, float* __restrict__ out2) {
  __shared__ float tile[32][68];
  const int bx = blockIdx.x;
  const int t = threadIdx.x;
  if (bx < 1024) {
    const int lx = bx & 63, cy = (bx >> 6) & 7, n = bx >> 9;
    const int l0 = lx * 64, c0 = cy * 32;
    const int g16 = n * 8 + cy;
    float s = 0.f, ss = 0.f;
#pragma unroll
    for (int i = 0; i < 16; i++) {
      s  += part[(g16 * 16 + i) * 2 + 0];
      ss += part[(g16 * 16 + i) * 2 + 1];
    }
    const float inv_cnt = 1.0f / (float)(CPG * LLEN);
    const float mu = s * inv_cnt;
    const float rsg = rsqrtf(ss * inv_cnt - mu * mu + GEPS);
    const int cl = t >> 3, l8 = t & 7;
    const float aa = rsg * w[c0 + cl];
    const float dd = b[c0 + cl] - mu * aa;
    const float* xrow = x + ((size_t)n * CCH + c0 + cl) * LLEN + l0;
#pragma unroll
    for (int i = 0; i < 2; i++) {
      const int ll = (l8 + 8 * i) * 4;
      float4 v = *(const float4*)(xrow + ll);
      v.x = fmaf(v.x, aa, dd);
      v.y = fmaf(v.y, aa, dd);
      v.z = fmaf(v.z, aa, dd);
      v.w = fmaf(v.w, aa, dd);
      *(float4*)&tile[cl][ll] = v;
    }
    __syncthreads();
    const int l = t & 63, cg = t >> 6;    // each wave owns one 8-channel group
    const int labs = l0 + l;
    bf16x8 ov;
#pragma unroll
    for (int j = 0; j < 8; j++) ov[j] = (short)f2b(tile[cg * 8 + j][l]);
    const size_t pos = (((size_t)n * 256 + (labs >> 4)) * 8 + (c0 >> 5)) * 512 +
                       ((labs & 15) + 16 * cg) * 8;
    *(bf16x8*)(xn16 + pos) = ov;
  } else if (bx < 1280) {
    const int sb = bx - 1024;
    const int idx = sb * 256 + t;              // float4 units; 65536 total
    const int m = idx >> 14;                   // block-uniform
    const int rem = idx & 16383;
    const int cout = rem >> 6;                 // 0..255
    const int ch4 = (rem & 63) << 2;           // 0..252
    const float* srcp = (m == 0) ? qw : (m == 1) ? kw : (m == 2) ? vw : pw;
    const float sc = (m == 0) ? QSCALE : 1.0f;
    const float4 v = ((const float4*)srcp)[(size_t)cout * 64 + (ch4 >> 2)];
    unsigned short* dst = w16 +
        ((size_t)(m * 16 + (cout >> 4)) * 8 + (ch4 >> 5)) * 512 +
        ((cout & 15) + 16 * ((ch4 >> 3) & 3)) * 8 + (ch4 & 7);
    uint2 wd;
    wd.x = cvtpk(v.x * sc, v.y * sc);
    wd.y = cvtpk(v.z * sc, v.w * sc);
    *(uint2*)dst = wd;                         // 8B-aligned: ch4&7 in {0,4}
    if (sb == 0) {
      bias_ws[t]       = qb[t] * QSCALE;
      bias_ws[256 + t] = kb[t];
      bias_ws[512 + t] = vb[t];
      bias_ws[768 + t] = pb[t];
    }
  } else {
    const int i = (bx - 1280) * 256 + t;
    out2[i] = (float)mask[i];
  }
}

// ------- KV GEMM (qkv v3 minus the q third — Q is fused into attn).
//   Grid (256, 2): blockIdx.y 0->K, 1->V. -------
__global__ __launch_bounds__(256, 4) void qkv_mfma_kernel(
    const unsigned short* __restrict__ xn16,
    const unsigned short* __restrict__ w16,
    const float* __restrict__ bias_ws,
    unsigned short* __restrict__ k16,
    unsigned short* __restrict__ v16) {
  const int t = threadIdx.x;
  const int lane = t & 63, wv = t >> 6;
  const int col = lane & 15, quad = lane >> 4;
  const int m0 = blockIdx.x * 32;            // 32 l-rows
  const int wsel = blockIdx.y + 1;           // 1=k, 2=v
  const int n = m0 >> 12;
  const int m16b = (m0 & 4095) >> 4;
  const int l0 = m0 & 4095;

  const unsigned short* xnb = xn16 + (((size_t)n * 256 + m16b) * 8) * 512 + lane * 8;
  const unsigned short* wb  = w16 + ((size_t)(wsel * 16 + wv * 4) * 8) * 512 + lane * 8;

  f32x4 acc[2][4];
#pragma unroll
  for (int mt = 0; mt < 2; mt++)
#pragma unroll
    for (int ct = 0; ct < 4; ct++) acc[mt][ct] = {0.f, 0.f, 0.f, 0.f};

#pragma unroll
  for (int kc = 0; kc < 8; kc++) {
    bf16x8 xf[2], wf[4];
    xf[0] = *(const bf16x8*)(xnb + (size_t)kc * 512);
    xf[1] = *(const bf16x8*)(xnb + (size_t)(8 + kc) * 512);
#pragma unroll
    for (int ct = 0; ct < 4; ct++)
      wf[ct] = *(const bf16x8*)(wb + (size_t)(ct * 8 + kc) * 512);
#pragma unroll
    for (int mt = 0; mt < 2; mt++)
#pragma unroll
      for (int ct = 0; ct < 4; ct++)
        acc[mt][ct] = (wsel == 1)
            ? __builtin_amdgcn_mfma_f32_16x16x32_bf16(wf[ct], xf[mt], acc[mt][ct], 0, 0, 0)   // D[cout][l]
            : __builtin_amdgcn_mfma_f32_16x16x32_bf16(xf[mt], wf[ct], acc[mt][ct], 0, 0, 0);  // D[key][vch]
  }

  if (wsel == 1) {
#pragma unroll
    for (int ct = 0; ct < 4; ct++) {
      const float4 b4 = *(const float4*)&bias_ws[wsel * CCH + wv * 64 + ct * 16 + quad * 4];
#pragma unroll
      for (int mt = 0; mt < 2; mt++) {
        uint2 wd;
        wd.x = cvtpk(acc[mt][ct][0] + b4.x, acc[mt][ct][1] + b4.y);
        wd.y = cvtpk(acc[mt][ct][2] + b4.z, acc[mt][ct][3] + b4.w);
        *(uint2*)(k16 + ((size_t)(n * 256 + m16b + mt) * 8 + wv * 2 + (ct >> 1)) * 512 +
                  (col + 16 * ((ct & 1) * 2 + (quad >> 1))) * 8 + (quad & 1) * 4) = wd;
      }
    }
  } else {
#pragma unroll
    for (int ct = 0; ct < 4; ct++) {
      const float bv = bias_ws[2 * CCH + wv * 64 + ct * 16 + col];
#pragma unroll
      for (int mt = 0; mt < 2; mt++) {
        uint2 wd;
        wd.x = cvtpk(acc[mt][ct][0] + bv, acc[mt][ct][1] + bv);
        wd.y = cvtpk(acc[mt][ct][2] + bv, acc[mt][ct][3] + bv);
        *(uint2*)(v16 + (((size_t)n * 128 + (l0 >> 5)) * 16 + wv * 4 + ct) * 512 +
                  (col + 16 * (mt * 2 + (quad >> 1))) * 8 + (quad & 1) * 4) = wd;
      }
    }
  }
}

// ------- Flash attention v10 = r4's v8 + fused Q prologue.
//   Each wave computes its own q-tile's B-frags from xn16/w16 (bitwise-
//   identical to the old qkv q-path: same mfma(wf,xf) kc-order, same
//   bias+cvtpk pairing), then routes D->B-frag layout with the SAME
//   permlane32/16 network already verified for P (wt<->kt, ch<->key).
//   Frags shared across the 4 waves via 8KB of shraw + one sync. -------
__global__ __launch_bounds__(256, 2) void attn_mfma_kernel(
    const unsigned short* __restrict__ xn16,  // xn tiled
    const unsigned short* __restrict__ w16,   // tiled weights (q at tiles 0..15)
    const float* __restrict__ bias_ws,        // q bias pre-scaled at [0..255]
    const unsigned short* __restrict__ k16,   // K' tiled
    const unsigned short* __restrict__ v16,   // V' tiled
    unsigned short* __restrict__ o16) {       // O' tiled (normalized)
  __shared__ __align__(16) unsigned char shraw[20480];
  f32x4 (*red)[4][64] = (f32x4 (*)[4][64])shraw;                      // 16KB
  f32x4 (*lred)[64] = (f32x4 (*)[64])(shraw + 16384);                 // 4KB
  bf16x8 (*qlds)[2][64] = (bf16x8 (*)[2][64])shraw;                   // 8KB (prologue reuse)
  const int t = threadIdx.x;
  const int lane = t & 63, wv = t >> 6;
  const int col = lane & 15, quad = lane >> 4;
  // Bijective XCD swizzle (512 blocks % 8 == 0): one head per XCD-L2.
  const int fid = blockIdx.y * gridDim.x + blockIdx.x;
  const int nh = fid & 7, qx = fid >> 3;
  const int n = nh >> 2, h = nh & 3;
  const int hc = h * HD;
  const int qt0 = qx * 4;                     // base q16-tile (64 rows)

  const unsigned short* xb = xn16 + (size_t)n * (256 * 8 * 512);
  const unsigned short* kb = k16 + (size_t)n * (256 * 8 * 512);
  const unsigned short* vb = v16 + (size_t)n * (128 * 16 * 512);

  bf16x8 bones;
#pragma unroll
  for (int i = 0; i < 8; i++) bones[i] = (short)0x3F80;   // bf16 1.0
  const f32x4 zf = {0.f, 0.f, 0.f, 0.f};

  // ---- Q prologue: wave wv computes q-tile (qt0+wv), shares via LDS ----
  {
    const unsigned short* xq = xb + ((size_t)(qt0 + wv) * 8) * 512 + lane * 8;
    bf16x8 xf[8];
#pragma unroll
    for (int kc = 0; kc < 8; kc++) xf[kc] = *(const bf16x8*)(xq + (size_t)kc * 512);
#pragma unroll
    for (int ks = 0; ks < 2; ks++) {
      const int g = h * 2 + ks;                // 32-cout group
      f32x4 da = zf, db = zf;                  // wt = 0, 1
#pragma unroll
      for (int kc = 0; kc < 8; kc++) {
        const bf16x8 wf0 = *(const bf16x8*)(w16 + ((size_t)((2 * g + 0) * 8 + kc)) * 512 + lane * 8);
        const bf16x8 wf1 = *(const bf16x8*)(w16 + ((size_t)((2 * g + 1) * 8 + kc)) * 512 + lane * 8);
        da = __builtin_amdgcn_mfma_f32_16x16x32_bf16(wf0, xf[kc], da, 0, 0, 0);  // D[cout][qrow]
        db = __builtin_amdgcn_mfma_f32_16x16x32_bf16(wf1, xf[kc], db, 0, 0, 0);
      }
      const float4 ba = *(const float4*)&bias_ws[g * 32 + 0 * 16 + quad * 4];
      const float4 bb = *(const float4*)&bias_ws[g * 32 + 1 * 16 + quad * 4];
      const unsigned a0 = cvtpk(da[0] + ba.x, da[1] + ba.y);
      const unsigned a1 = cvtpk(da[2] + ba.z, da[3] + ba.w);
      const unsigned b0 = cvtpk(db[0] + bb.x, db[1] + bb.y);
      const unsigned b1 = cvtpk(db[2] + bb.z, db[3] + bb.w);
      auto r0 = __builtin_amdgcn_permlane32_swap(a0, b0, false, false);
      auto s0 = __builtin_amdgcn_permlane16_swap(r0[0], r0[1], false, false);
      auto r1 = __builtin_amdgcn_permlane32_swap(a1, b1, false, false);
      auto s1 = __builtin_amdgcn_permlane16_swap(r1[0], r1[1], false, false);
      union { unsigned u[4]; bf16x8 v; } pu;
      pu.u[0] = s0[0];
      pu.u[1] = s1[0];
      pu.u[2] = s0[1];
      pu.u[3] = s1[1];
      qlds[wv][ks][lane] = pu.v;
    }
  }
  __syncthreads();
  bf16x8 bq[4][2];
#pragma unroll
  for (int qt = 0; qt < 4; qt++)
#pragma unroll
    for (int ks = 0; ks < 2; ks++) bq[qt][ks] = qlds[qt][ks][lane];

  f32x4 o[4][4], lacc[4];
#pragma unroll
  for (int qt = 0; qt < 4; qt++) {
    lacc[qt] = {0.f, 0.f, 0.f, 0.f};
#pragma unroll
    for (int ct = 0; ct < 4; ct++) o[qt][ct] = {0.f, 0.f, 0.f, 0.f};
  }

  // Wave-base pointers; advance by 8192 ushorts (16KB) per 32-key chunk.
  const unsigned short* kp = kb + ((size_t)(wv * 64) * 8 + h * 2) * 512 + lane * 8;
  const unsigned short* vp = vb + ((size_t)(wv * 32) * 16 + h * 4) * 512 + lane * 8;

  bf16x8 kA[2][2], kB[2][2], vA[4], vB[4];
  auto loadK = [&](bf16x8 (&kr)[2][2], const unsigned short* p) {
#pragma unroll
    for (int kt = 0; kt < 2; kt++)
#pragma unroll
      for (int ks = 0; ks < 2; ks++)
        kr[kt][ks] = *(const bf16x8*)(p + kt * 4096 + ks * 512);
  };
  auto loadV = [&](bf16x8 (&vv)[4], const unsigned short* p) {
#pragma unroll
    for (int ct = 0; ct < 4; ct++) vv[ct] = *(const bf16x8*)(p + ct * 512);
  };

  auto chunk = [&](bf16x8 (&kr)[2][2], bf16x8 (&vv)[4]) {
    // S^T = K·Q^T; p = 2^s packed to bf16; permlane exchange -> PV A-frags.
    bf16x8 pa[4];
#pragma unroll
    for (int qt = 0; qt < 4; qt++) {
      unsigned a0, a1, b0, b1;
      {
        f32x4 s = __builtin_amdgcn_mfma_f32_16x16x32_bf16(kr[0][0], bq[qt][0], zf, 0, 0, 0);
        s = __builtin_amdgcn_mfma_f32_16x16x32_bf16(kr[0][1], bq[qt][1], s, 0, 0, 0);
        a0 = cvtpk(exp2_(s[0]), exp2_(s[1]));
        a1 = cvtpk(exp2_(s[2]), exp2_(s[3]));
      }
      {
        f32x4 s = __builtin_amdgcn_mfma_f32_16x16x32_bf16(kr[1][0], bq[qt][0], zf, 0, 0, 0);
        s = __builtin_amdgcn_mfma_f32_16x16x32_bf16(kr[1][1], bq[qt][1], s, 0, 0, 0);
        b0 = cvtpk(exp2_(s[0]), exp2_(s[1]));
        b1 = cvtpk(exp2_(s[2]), exp2_(s[3]));
      }
      auto r0 = __builtin_amdgcn_permlane32_swap(a0, b0, false, false);
      auto s0 = __builtin_amdgcn_permlane16_swap(r0[0], r0[1], false, false);
      auto r1 = __builtin_amdgcn_permlane32_swap(a1, b1, false, false);
      auto s1 = __builtin_amdgcn_permlane16_swap(r1[0], r1[1], false, false);
      union { unsigned u[4]; bf16x8 v; } pu;
      pu.u[0] = s0[0];   // w0 = keys 8q'+0,1
      pu.u[1] = s1[0];   // w1 = keys 8q'+2,3
      pu.u[2] = s0[1];   // w2 = keys 8q'+4,5
      pu.u[3] = s1[1];   // w3 = keys 8q'+6,7
      pa[qt] = pu.v;
    }
    // PV + denominators — pure MFMA cluster
    __builtin_amdgcn_s_setprio(1);
#pragma unroll
    for (int qt = 0; qt < 4; qt++) {
      lacc[qt] = __builtin_amdgcn_mfma_f32_16x16x32_bf16(pa[qt], bones, lacc[qt], 0, 0, 0);
#pragma unroll
      for (int ct = 0; ct < 4; ct++)
        o[qt][ct] = __builtin_amdgcn_mfma_f32_16x16x32_bf16(pa[qt], vv[ct], o[qt][ct], 0, 0, 0);
    }
    __builtin_amdgcn_s_setprio(0);
  };

  loadK(kA, kp);
  loadV(vA, vp);
  for (int it = 0; it < 30; it += 2) {
    loadK(kB, kp + 8192);
    loadV(vB, vp + 8192);
    chunk(kA, vA);
    kp += 16384;
    vp += 16384;
    loadK(kA, kp);
    loadV(vA, vp);
    chunk(kB, vB);
  }
  loadK(kB, kp + 8192);
  loadV(vB, vp + 8192);
  chunk(kA, vA);
  chunk(kB, vB);

  // ---- merge across 4 waves, normalize, store O' tiled ----
  const int cch = hc + wv * 16 + col;        // channel this thread stores
  const int lquad16 = 16 * ((cch >> 3) & 3);
  const size_t ctile = cch >> 5;
#pragma unroll
  for (int qt = 0; qt < 4; qt++) {
    __syncthreads();
#pragma unroll
    for (int ct = 0; ct < 4; ct++) red[wv][ct][lane] = o[qt][ct];
    lred[wv][lane] = lacc[qt];
    __syncthreads();
    f32x4 os = red[0][wv][lane];
    os += red[1][wv][lane];
    os += red[2][wv][lane];
    os += red[3][wv][lane];
    f32x4 ls = lred[0][lane];
    ls += lred[1][lane];
    ls += lred[2][lane];
    ls += lred[3][lane];
    const size_t base = (((size_t)n * 256 + qt0 + qt) * 8 + ctile) * 512 + (cch & 7);
#pragma unroll
    for (int r = 0; r < 4; r++)
      o16[base + ((quad * 4 + r) + lquad16) * 8] = f2b(os[r] / ls[r]);
  }
}

// ------- Proj GEMM, 32-row M-tiles (unchanged). -------
__global__ __launch_bounds__(256, 4) void proj_mfma_kernel(
    const unsigned short* __restrict__ o16,
    const unsigned short* __restrict__ w16,
    const float* __restrict__ pbias,
    const float* __restrict__ x,
    float* __restrict__ out) {
  const int t = threadIdx.x;
  const int lane = t & 63, wv = t >> 6;
  const int col = lane & 15, quad = lane >> 4;
  const int m0 = blockIdx.x * 32;
  const int by = blockIdx.y;
  const int co0 = by * 64;
  const int n = m0 >> 12, l0 = m0 & 4095;

  const unsigned short* ob = o16 + (size_t)n * (256 * 8 * 512);
  const unsigned short* wb = w16 + ((size_t)(48 + by * 4 + wv) * 8) * 512 + lane * 8;

  f32x4 acc[2];
#pragma unroll
  for (int i = 0; i < 2; i++) acc[i] = {0.f, 0.f, 0.f, 0.f};

#pragma unroll
  for (int kc = 0; kc < 8; kc++) {
    const bf16x8 aw = *(const bf16x8*)(wb + (size_t)kc * 512);
#pragma unroll
    for (int lt = 0; lt < 2; lt++) {
      const bf16x8 bo = *(const bf16x8*)(ob + ((size_t)((l0 >> 4) + lt) * 8 + kc) * 512 + lane * 8);
      acc[lt] = __builtin_amdgcn_mfma_f32_16x16x32_bf16(aw, bo, acc[lt], 0, 0, 0);  // D[cout][l]
    }
  }
#pragma unroll
  for (int lt = 0; lt < 2; lt++)
#pragma unroll
    for (int r = 0; r < 4; r++) {
      const int cout = co0 + wv * 16 + quad * 4 + r;
      const size_t idx = ((size_t)(n * CCH + cout)) * LLEN + l0 + lt * 16 + col;
      out[idx] = acc[lt][r] + pbias[cout] + x[idx];
    }
}

extern "C" void kernel_launch(void* const* d_in, const int* in_sizes, int n_in,
                              void* d_out, int out_size, void* d_ws, size_t ws_size,
                              hipStream_t stream) {
  (void)in_sizes; (void)n_in; (void)out_size; (void)ws_size;
  const float* x      = (const float*)d_in[0];
  const int*   mask   = (const int*)d_in[1];
  const float* norm_w = (const float*)d_in[2];
  const float* norm_b = (const float*)d_in[3];
  const float* q_w    = (const float*)d_in[4];
  const float* q_b    = (const float*)d_in[5];
  const float* k_w    = (const float*)d_in[6];
  const float* k_b    = (const float*)d_in[7];
  const float* v_w    = (const float*)d_in[8];
  const float* v_b    = (const float*)d_in[9];
  const float* p_w    = (const float*)d_in[10];
  const float* p_b    = (const float*)d_in[11];

  const size_t TSZ = (size_t)NBATCH * LLEN * CCH;   // 2097152 elements
  unsigned short* xn16 = (unsigned short*)d_ws;     // TSZ (tiled)
  unsigned short* k16  = xn16 + TSZ;                // tiled
  unsigned short* v16  = k16 + TSZ;                 // tiled
  unsigned short* o16  = v16 + TSZ;                 // tiled
  unsigned short* w16  = o16 + TSZ;                 // 4*65536 (tiled)
  float* bias_ws = (float*)(w16 + 4 * 65536);       // 1024 floats
  float* part    = bias_ws + 1024;                  // 512
  // total ~19 MB

  float* out  = (float*)d_out;
  float* out2 = out + TSZ;   // mask chunk

  setup_kernel<<<256, 256, 0, stream>>>(x, part);
  gn_apply_kernel<<<1312, 256, 0, stream>>>(
      x, norm_w, norm_b, part, q_w, k_w, v_w, p_w, q_b, k_b, v_b, p_b,
      mask, xn16, w16, bias_ws, out2);
  qkv_mfma_kernel<<<dim3((NBATCH * LLEN) / 32, 2), 256, 0, stream>>>(
      xn16, w16, bias_ws, k16, v16);
  attn_mfma_kernel<<<dim3(LLEN / 64, NBATCH * NHEAD), 256, 0, stream>>>(
      xn16, w16, bias_ws, k16, v16, o16);
  proj_mfma_kernel<<<dim3((NBATCH * LLEN) / 32, CCH / 64), 256, 0, stream>>>(
      o16, w16, bias_ws + 768, x, out);
}

// Round 9
// 142.819 us; speedup vs baseline: 2.0217x; 1.0063x over previous
//
#include <hip/hip_runtime.h>
#include <hip/hip_bf16.h>

// Problem constants (N=2, C=256, H=W=64) — float32 I/O per reference.
#define NBATCH 2
#define CCH    256
#define LLEN   4096      // H*W
#define NGROUP 8
#define CPG    32        // C / NGROUP
#define NHEAD  4
#define HD     64        // C / NHEAD
#define GEPS   1e-5f
// q pre-scale: hd^-0.5 * log2(e); scores feed v_exp_f32 (2^x) directly.
#define QSCALE 0.18033688011112042f

// Generic MFMA fragment tiling (for 16x16x32 bf16): a [R x 256ch] tensor is
// stored as tiles [r16][c32] of 512 ushorts; element (r, c) sits at
// tile*512 + ((r&15) + 16*((c>>3)&3))*8 + (c&7).
//
// SESSION LEDGER (best = this configuration, 142.3us, r4):
//  - attn: 49.6 -> 41.3us via in-register P (permlane) + native v_cvt_pk
//    (software RNE pack was ~10 VALU/pack — the hidden VALUBusy).
//    Plateau: VALU(exp2-minimal softmax) ~= MFMA demand, serial chain,
//    2 waves/SIMD; 4 schedule variants all 41-49us.
//  - XCD swizzle (head = fid&7): FETCH 35 -> 6.2MB, K/V L2-resident.
//  - Fusion experiments FAILED: spin-barrier GN (r5: reg-cap spill; r7:
//    cross-XCD release fences = 174us). Kernel boundary IS the cheap sync.
//  - Q-fused-into-attn (r8): bitwise-correct, net-neutral (+3 attn / -2 qkv).

typedef short bf16x8 __attribute__((ext_vector_type(8)));
typedef float f32x4  __attribute__((ext_vector_type(4)));

__device__ __forceinline__ unsigned short f2b(float f) {
  unsigned u = __float_as_uint(f);
  u += 0x7FFFu + ((u >> 16) & 1u);
  return (unsigned short)(u >> 16);
}
// Native packed f32->bf16 convert (gfx950): 1 instr vs ~10 VALU for the
// header's software RNE path. Low half = first operand.
__device__ __forceinline__ unsigned cvtpk(float lo, float hi) {
  unsigned r;
  asm("v_cvt_pk_bf16_f32 %0, %1, %2" : "=v"(r) : "v"(lo), "v"(hi));
  return r;
}
__device__ __forceinline__ float exp2_(float x) {
#if __has_builtin(__builtin_amdgcn_exp2f)
  return __builtin_amdgcn_exp2f(x);
#else
  return exp2f(x);
#endif
}

// ------- setup: GN partial sums only (256 blocks, 16 per group) -------
__global__ __launch_bounds__(256) void setup_kernel(const float* __restrict__ x,
                                                    float* __restrict__ part) {
  __shared__ float rs[4], rss[4];
  const int sb = blockIdx.x;
  const int t = threadIdx.x;
  const int gidx = sb >> 4, sub = sb & 15;
  const float4* xp = (const float4*)(x + (size_t)gidx * (CPG * LLEN)) + (size_t)sub * 2048;
  float s = 0.f, ss = 0.f;
  for (int i = t; i < 2048; i += 256) {
    const float4 v = xp[i];
    s += v.x + v.y + v.z + v.w;
    ss = fmaf(v.x, v.x, ss);
    ss = fmaf(v.y, v.y, ss);
    ss = fmaf(v.z, v.z, ss);
    ss = fmaf(v.w, v.w, ss);
  }
#pragma unroll
  for (int off = 32; off; off >>= 1) {
    s  += __shfl_down(s, off);
    ss += __shfl_down(ss, off);
  }
  if ((t & 63) == 0) { rs[t >> 6] = s; rss[t >> 6] = ss; }
  __syncthreads();
  if (t == 0) {
    part[sb * 2 + 0] = rs[0] + rs[1] + rs[2] + rs[3];
    part[sb * 2 + 1] = rss[0] + rss[1] + rss[2] + rss[3];
  }
}

// ------- GN apply+transpose (blocks 0..1023) | weight tiling+bias
//   (1024..1279) | mask copy (1280..1311). -------
__global__ __launch_bounds__(256) void gn_apply_kernel(
    const float* __restrict__ x, const float* __restrict__ w,
    const float* __restrict__ b, const float* __restrict__ part,
    const float* __restrict__ qw, const float* __restrict__ kw,
    const float* __restrict__ vw, const float* __restrict__ pw,
    const float* __restrict__ qb, const float* __restrict__ kb,
    const float* __restrict__ vb, const float* __restrict__ pb,
    const int* __restrict__ mask,
    unsigned short* __restrict__ xn16, unsigned short* __restrict__ w16,
    float* __restrict__ bias_ws, float* __restrict__ out2) {
  __shared__ float tile[32][68];
  const int bx = blockIdx.x;
  const int t = threadIdx.x;
  if (bx < 1024) {
    const int lx = bx & 63, cy = (bx >> 6) & 7, n = bx >> 9;
    const int l0 = lx * 64, c0 = cy * 32;
    const int g16 = n * 8 + cy;
    float s = 0.f, ss = 0.f;
#pragma unroll
    for (int i = 0; i < 16; i++) {
      s  += part[(g16 * 16 + i) * 2 + 0];
      ss += part[(g16 * 16 + i) * 2 + 1];
    }
    const float inv_cnt = 1.0f / (float)(CPG * LLEN);
    const float mu = s * inv_cnt;
    const float rsg = rsqrtf(ss * inv_cnt - mu * mu + GEPS);
    const int cl = t >> 3, l8 = t & 7;
    const float aa = rsg * w[c0 + cl];
    const float dd = b[c0 + cl] - mu * aa;
    const float* xrow = x + ((size_t)n * CCH + c0 + cl) * LLEN + l0;
#pragma unroll
    for (int i = 0; i < 2; i++) {
      const int ll = (l8 + 8 * i) * 4;
      float4 v = *(const float4*)(xrow + ll);
      v.x = fmaf(v.x, aa, dd);
      v.y = fmaf(v.y, aa, dd);
      v.z = fmaf(v.z, aa, dd);
      v.w = fmaf(v.w, aa, dd);
      *(float4*)&tile[cl][ll] = v;
    }
    __syncthreads();
    const int l = t & 63, cg = t >> 6;    // each wave owns one 8-channel group
    const int labs = l0 + l;
    bf16x8 ov;
#pragma unroll
    for (int j = 0; j < 8; j++) ov[j] = (short)f2b(tile[cg * 8 + j][l]);
    const size_t pos = (((size_t)n * 256 + (labs >> 4)) * 8 + (c0 >> 5)) * 512 +
                       ((labs & 15) + 16 * cg) * 8;
    *(bf16x8*)(xn16 + pos) = ov;
  } else if (bx < 1280) {
    const int sb = bx - 1024;
    const int idx = sb * 256 + t;              // float4 units; 65536 total
    const int m = idx >> 14;                   // block-uniform
    const int rem = idx & 16383;
    const int cout = rem >> 6;                 // 0..255
    const int ch4 = (rem & 63) << 2;           // 0..252
    // no runtime-indexed pointer array (rule #20 scratch hazard)
    const float* srcp = (m == 0) ? qw : (m == 1) ? kw : (m == 2) ? vw : pw;
    const float sc = (m == 0) ? QSCALE : 1.0f;
    const float4 v = ((const float4*)srcp)[(size_t)cout * 64 + (ch4 >> 2)];
    unsigned short* dst = w16 +
        ((size_t)(m * 16 + (cout >> 4)) * 8 + (ch4 >> 5)) * 512 +
        ((cout & 15) + 16 * ((ch4 >> 3) & 3)) * 8 + (ch4 & 7);
    uint2 wd;
    wd.x = cvtpk(v.x * sc, v.y * sc);
    wd.y = cvtpk(v.z * sc, v.w * sc);
    *(uint2*)dst = wd;                         // 8B-aligned: ch4&7 in {0,4}
    if (sb == 0) {
      bias_ws[t]       = qb[t] * QSCALE;
      bias_ws[256 + t] = kb[t];
      bias_ws[512 + t] = vb[t];
      bias_ws[768 + t] = pb[t];
    }
  } else {
    const int i = (bx - 1280) * 256 + t;
    out2[i] = (float)mask[i];
  }
}

// ------- QKV GEMM v3: MFMA orientation per output so each lane's 4 acc
//   values are 4 CONSECUTIVE ushorts in the tiled layout: epilogue =
//   16 cvtpk + 8 uint2 stores. -------
__global__ __launch_bounds__(256, 4) void qkv_mfma_kernel(
    const unsigned short* __restrict__ xn16,
    const unsigned short* __restrict__ w16,
    const float* __restrict__ bias_ws,
    unsigned short* __restrict__ q16,
    unsigned short* __restrict__ k16,
    unsigned short* __restrict__ v16) {
  const int t = threadIdx.x;
  const int lane = t & 63, wv = t >> 6;
  const int col = lane & 15, quad = lane >> 4;
  const int m0 = blockIdx.x * 32;            // 32 l-rows
  const int wsel = blockIdx.y;               // 0=q,1=k,2=v
  const int n = m0 >> 12;
  const int m16b = (m0 & 4095) >> 4;
  const int l0 = m0 & 4095;

  const unsigned short* xnb = xn16 + (((size_t)n * 256 + m16b) * 8) * 512 + lane * 8;
  const unsigned short* wb  = w16 + ((size_t)(wsel * 16 + wv * 4) * 8) * 512 + lane * 8;

  f32x4 acc[2][4];
#pragma unroll
  for (int mt = 0; mt < 2; mt++)
#pragma unroll
    for (int ct = 0; ct < 4; ct++) acc[mt][ct] = {0.f, 0.f, 0.f, 0.f};

#pragma unroll
  for (int kc = 0; kc < 8; kc++) {
    bf16x8 xf[2], wf[4];
    xf[0] = *(const bf16x8*)(xnb + (size_t)kc * 512);
    xf[1] = *(const bf16x8*)(xnb + (size_t)(8 + kc) * 512);
#pragma unroll
    for (int ct = 0; ct < 4; ct++)
      wf[ct] = *(const bf16x8*)(wb + (size_t)(ct * 8 + kc) * 512);
#pragma unroll
    for (int mt = 0; mt < 2; mt++)
#pragma unroll
      for (int ct = 0; ct < 4; ct++)
        acc[mt][ct] = (wsel < 2)
            ? __builtin_amdgcn_mfma_f32_16x16x32_bf16(wf[ct], xf[mt], acc[mt][ct], 0, 0, 0)   // D[cout][l]
            : __builtin_amdgcn_mfma_f32_16x16x32_bf16(xf[mt], wf[ct], acc[mt][ct], 0, 0, 0);  // D[key][vch]
  }

  if (wsel < 2) {
    // D[cout][l]: lane(col=l, quad), r -> cout = wv*64 + ct*16 + quad*4 + r.
    unsigned short* dst = (wsel == 0) ? q16 : k16;
#pragma unroll
    for (int ct = 0; ct < 4; ct++) {
      const float4 b4 = *(const float4*)&bias_ws[wsel * CCH + wv * 64 + ct * 16 + quad * 4];
#pragma unroll
      for (int mt = 0; mt < 2; mt++) {
        uint2 wd;
        wd.x = cvtpk(acc[mt][ct][0] + b4.x, acc[mt][ct][1] + b4.y);
        wd.y = cvtpk(acc[mt][ct][2] + b4.z, acc[mt][ct][3] + b4.w);
        *(uint2*)(dst + ((size_t)(n * 256 + m16b + mt) * 8 + wv * 2 + (ct >> 1)) * 512 +
                  (col + 16 * ((ct & 1) * 2 + (quad >> 1))) * 8 + (quad & 1) * 4) = wd;
      }
    }
  } else {
    // D[key][vch]: lane(col=vch, quad), r -> key = l0 + mt*16 + quad*4 + r.
#pragma unroll
    for (int ct = 0; ct < 4; ct++) {
      const float bv = bias_ws[2 * CCH + wv * 64 + ct * 16 + col];
#pragma unroll
      for (int mt = 0; mt < 2; mt++) {
        uint2 wd;
        wd.x = cvtpk(acc[mt][ct][0] + bv, acc[mt][ct][1] + bv);
        wd.y = cvtpk(acc[mt][ct][2] + bv, acc[mt][ct][3] + bv);
        *(uint2*)(v16 + (((size_t)n * 128 + (l0 >> 5)) * 16 + wv * 4 + ct) * 512 +
                  (col + 16 * (mt * 2 + (quad >> 1))) * 8 + (quad & 1) * 4) = wd;
      }
    }
  }
}

// ------- Flash attention v8: qt=4, XCD swizzle, K/V reg ping-pong,
//   in-register P via NATIVE v_cvt_pk_bf16_f32 + permlane. -------
__global__ __launch_bounds__(256, 2) void attn_mfma_kernel(
    const unsigned short* __restrict__ q16,   // Q' tiled, pre-scaled
    const unsigned short* __restrict__ k16,   // K' tiled
    const unsigned short* __restrict__ v16,   // V' tiled
    unsigned short* __restrict__ o16) {       // O' tiled (normalized)
  __shared__ __align__(16) unsigned char shraw[20480];
  f32x4 (*red)[4][64] = (f32x4 (*)[4][64])shraw;                      // [srcwv][ct][lane] 16KB
  f32x4 (*lred)[64] = (f32x4 (*)[64])(shraw + 16384);                 // [srcwv][lane] 4KB
  const int t = threadIdx.x;
  const int lane = t & 63, wv = t >> 6;
  const int col = lane & 15, quad = lane >> 4;
  // Bijective XCD swizzle (512 blocks % 8 == 0): head = fid&7 -> one head
  // per XCD, its 1MB K/V resident in that XCD's private 4MB L2.
  const int fid = blockIdx.y * gridDim.x + blockIdx.x;
  const int nh = fid & 7, qx = fid >> 3;
  const int n = nh >> 2, h = nh & 3;
  const int hc = h * HD;
  const int qt0 = qx * 4;                     // base q16-tile (4 tiles = 64 rows)

  const unsigned short* qb = q16 + (size_t)n * (256 * 8 * 512);
  const unsigned short* kb = k16 + (size_t)n * (256 * 8 * 512);
  const unsigned short* vb = v16 + (size_t)n * (128 * 16 * 512);

  // Q B-frags (shared by all waves)
  bf16x8 bq[4][2];
#pragma unroll
  for (int qt = 0; qt < 4; qt++)
#pragma unroll
    for (int ks = 0; ks < 2; ks++)
      bq[qt][ks] = *(const bf16x8*)(qb + ((size_t)(qt0 + qt) * 8 + h * 2 + ks) * 512 + lane * 8);

  bf16x8 bones;
#pragma unroll
  for (int i = 0; i < 8; i++) bones[i] = (short)0x3F80;   // bf16 1.0
  const f32x4 zf = {0.f, 0.f, 0.f, 0.f};      // persistent zero C-operand

  f32x4 o[4][4], lacc[4];
#pragma unroll
  for (int qt = 0; qt < 4; qt++) {
    lacc[qt] = {0.f, 0.f, 0.f, 0.f};
#pragma unroll
    for (int ct = 0; ct < 4; ct++) o[qt][ct] = {0.f, 0.f, 0.f, 0.f};
  }

  // Wave-base pointers; advance by 8192 ushorts (16KB) per 32-key chunk.
  const unsigned short* kp = kb + ((size_t)(wv * 64) * 8 + h * 2) * 512 + lane * 8;
  const unsigned short* vp = vb + ((size_t)(wv * 32) * 16 + h * 4) * 512 + lane * 8;

  bf16x8 kA[2][2], kB[2][2], vA[4], vB[4];
  auto loadK = [&](bf16x8 (&kr)[2][2], const unsigned short* p) {
#pragma unroll
    for (int kt = 0; kt < 2; kt++)
#pragma unroll
      for (int ks = 0; ks < 2; ks++)
        kr[kt][ks] = *(const bf16x8*)(p + kt * 4096 + ks * 512);
  };
  auto loadV = [&](bf16x8 (&vv)[4], const unsigned short* p) {
#pragma unroll
    for (int ct = 0; ct < 4; ct++) vv[ct] = *(const bf16x8*)(p + ct * 512);
  };

  auto chunk = [&](bf16x8 (&kr)[2][2], bf16x8 (&vv)[4]) {
    // S^T = K·Q^T; p = 2^s packed to bf16; permlane exchange -> PV A-frags.
    bf16x8 pa[4];
#pragma unroll
    for (int qt = 0; qt < 4; qt++) {
      unsigned a0, a1, b0, b1;
      {
        f32x4 s = __builtin_amdgcn_mfma_f32_16x16x32_bf16(kr[0][0], bq[qt][0], zf, 0, 0, 0);
        s = __builtin_amdgcn_mfma_f32_16x16x32_bf16(kr[0][1], bq[qt][1], s, 0, 0, 0);
        a0 = cvtpk(exp2_(s[0]), exp2_(s[1]));
        a1 = cvtpk(exp2_(s[2]), exp2_(s[3]));
      }
      {
        f32x4 s = __builtin_amdgcn_mfma_f32_16x16x32_bf16(kr[1][0], bq[qt][0], zf, 0, 0, 0);
        s = __builtin_amdgcn_mfma_f32_16x16x32_bf16(kr[1][1], bq[qt][1], s, 0, 0, 0);
        b0 = cvtpk(exp2_(s[0]), exp2_(s[1]));
        b1 = cvtpk(exp2_(s[2]), exp2_(s[3]));
      }
      auto r0 = __builtin_amdgcn_permlane32_swap(a0, b0, false, false);
      auto s0 = __builtin_amdgcn_permlane16_swap(r0[0], r0[1], false, false);
      auto r1 = __builtin_amdgcn_permlane32_swap(a1, b1, false, false);
      auto s1 = __builtin_amdgcn_permlane16_swap(r1[0], r1[1], false, false);
      union { unsigned u[4]; bf16x8 v; } pu;
      pu.u[0] = s0[0];   // w0 = keys 8q'+0,1
      pu.u[1] = s1[0];   // w1 = keys 8q'+2,3
      pu.u[2] = s0[1];   // w2 = keys 8q'+4,5
      pu.u[3] = s1[1];   // w3 = keys 8q'+6,7
      pa[qt] = pu.v;
    }
    // PV + denominators — pure MFMA cluster
    __builtin_amdgcn_s_setprio(1);
#pragma unroll
    for (int qt = 0; qt < 4; qt++) {
      lacc[qt] = __builtin_amdgcn_mfma_f32_16x16x32_bf16(pa[qt], bones, lacc[qt], 0, 0, 0);
#pragma unroll
      for (int ct = 0; ct < 4; ct++)
        o[qt][ct] = __builtin_amdgcn_mfma_f32_16x16x32_bf16(pa[qt], vv[ct], o[qt][ct], 0, 0, 0);
    }
    __builtin_amdgcn_s_setprio(0);
  };

  loadK(kA, kp);
  loadV(vA, vp);
  for (int it = 0; it < 30; it += 2) {
    loadK(kB, kp + 8192);
    loadV(vB, vp + 8192);
    chunk(kA, vA);
    kp += 16384;
    vp += 16384;
    loadK(kA, kp);
    loadV(vA, vp);
    chunk(kB, vB);
  }
  loadK(kB, kp + 8192);
  loadV(vB, vp + 8192);
  chunk(kA, vA);
  chunk(kB, vB);

  // ---- merge across 4 waves, normalize, store O' tiled ----
  const int cch = hc + wv * 16 + col;        // channel this thread stores
  const int lquad16 = 16 * ((cch >> 3) & 3);
  const size_t ctile = cch >> 5;
#pragma unroll
  for (int qt = 0; qt < 4; qt++) {
    __syncthreads();
#pragma unroll
    for (int ct = 0; ct < 4; ct++) red[wv][ct][lane] = o[qt][ct];
    lred[wv][lane] = lacc[qt];
    __syncthreads();
    f32x4 os = red[0][wv][lane];
    os += red[1][wv][lane];
    os += red[2][wv][lane];
    os += red[3][wv][lane];
    f32x4 ls = lred[0][lane];
    ls += lred[1][lane];
    ls += lred[2][lane];
    ls += lred[3][lane];
    const size_t base = (((size_t)n * 256 + qt0 + qt) * 8 + ctile) * 512 + (cch & 7);
#pragma unroll
    for (int r = 0; r < 4; r++)
      o16[base + ((quad * 4 + r) + lquad16) * 8] = f2b(os[r] / ls[r]);
  }
}

// ------- Proj GEMM, 32-row M-tiles, register MFMA + bias + residual -> fp32 out -------
__global__ __launch_bounds__(256, 4) void proj_mfma_kernel(
    const unsigned short* __restrict__ o16,     // O' tiled
    const unsigned short* __restrict__ w16,     // tiled weights (pw at tile 48)
    const float* __restrict__ pbias,
    const float* __restrict__ x,
    float* __restrict__ out) {
  const int t = threadIdx.x;
  const int lane = t & 63, wv = t >> 6;
  const int col = lane & 15, quad = lane >> 4;
  const int m0 = blockIdx.x * 32;            // l rows
  const int by = blockIdx.y;
  const int co0 = by * 64;
  const int n = m0 >> 12, l0 = m0 & 4095;

  const unsigned short* ob = o16 + (size_t)n * (256 * 8 * 512);
  const unsigned short* wb = w16 + ((size_t)(48 + by * 4 + wv) * 8) * 512 + lane * 8;

  f32x4 acc[2];
#pragma unroll
  for (int i = 0; i < 2; i++) acc[i] = {0.f, 0.f, 0.f, 0.f};

#pragma unroll
  for (int kc = 0; kc < 8; kc++) {
    const bf16x8 aw = *(const bf16x8*)(wb + (size_t)kc * 512);
#pragma unroll
    for (int lt = 0; lt < 2; lt++) {
      const bf16x8 bo = *(const bf16x8*)(ob + ((size_t)((l0 >> 4) + lt) * 8 + kc) * 512 + lane * 8);
      acc[lt] = __builtin_amdgcn_mfma_f32_16x16x32_bf16(aw, bo, acc[lt], 0, 0, 0);  // D[cout][l]
    }
  }
#pragma unroll
  for (int lt = 0; lt < 2; lt++)
#pragma unroll
    for (int r = 0; r < 4; r++) {
      const int cout = co0 + wv * 16 + quad * 4 + r;
      const size_t idx = ((size_t)(n * CCH + cout)) * LLEN + l0 + lt * 16 + col;
      out[idx] = acc[lt][r] + pbias[cout] + x[idx];
    }
}

extern "C" void kernel_launch(void* const* d_in, const int* in_sizes, int n_in,
                              void* d_out, int out_size, void* d_ws, size_t ws_size,
                              hipStream_t stream) {
  (void)in_sizes; (void)n_in; (void)out_size; (void)ws_size;
  const float* x      = (const float*)d_in[0];
  const int*   mask   = (const int*)d_in[1];
  const float* norm_w = (const float*)d_in[2];
  const float* norm_b = (const float*)d_in[3];
  const float* q_w    = (const float*)d_in[4];
  const float* q_b    = (const float*)d_in[5];
  const float* k_w    = (const float*)d_in[6];
  const float* k_b    = (const float*)d_in[7];
  const float* v_w    = (const float*)d_in[8];
  const float* v_b    = (const float*)d_in[9];
  const float* p_w    = (const float*)d_in[10];
  const float* p_b    = (const float*)d_in[11];

  const size_t TSZ = (size_t)NBATCH * LLEN * CCH;   // 2097152 elements
  unsigned short* xn16 = (unsigned short*)d_ws;     // TSZ (tiled)
  unsigned short* q16  = xn16 + TSZ;                // tiled
  unsigned short* k16  = q16 + TSZ;                 // tiled
  unsigned short* v16  = k16 + TSZ;                 // tiled
  unsigned short* o16  = v16 + TSZ;                 // tiled
  unsigned short* w16  = o16 + TSZ;                 // 4*65536 (tiled)
  float* bias_ws = (float*)(w16 + 4 * 65536);       // 1024 floats
  float* part    = bias_ws + 1024;                  // 512
  // total ~21 MB

  float* out  = (float*)d_out;
  float* out2 = out + TSZ;   // mask chunk

  setup_kernel<<<256, 256, 0, stream>>>(x, part);
  gn_apply_kernel<<<1312, 256, 0, stream>>>(
      x, norm_w, norm_b, part, q_w, k_w, v_w, p_w, q_b, k_b, v_b, p_b,
      mask, xn16, w16, bias_ws, out2);
  qkv_mfma_kernel<<<dim3((NBATCH * LLEN) / 32, 3), 256, 0, stream>>>(
      xn16, w16, bias_ws, q16, k16, v16);
  attn_mfma_kernel<<<dim3(LLEN / 64, NBATCH * NHEAD), 256, 0, stream>>>(
      q16, k16, v16, o16);
  proj_mfma_kernel<<<dim3((NBATCH * LLEN) / 32, CCH / 64), 256, 0, stream>>>(
      o16, w16, bias_ws + 768, x, out);
}